// Round 11
// baseline (511.379 us; speedup 1.0000x reference)
//
#include <hip/hip_runtime.h>

#define DD 128
#define HH 512
#define WW 512
#define NVOX (DD*HH*WW)          // 33554432
#define THRESHV 0.997f
#define KPEAKS 131072
#define CAND_CAP (1u<<19)        // 524288 candidate slots (expect ~100K)
#define PEAK_CAP (1u<<18)        // 262144 peak slots (expect ~63K)
#define NBINS 65536

// peaks all lie in (0.997, 1.0): float bits have constant upper 16 bits
// 0x3F7F -> low 16 bits monotone in value. bin=(~bits)&0xFFFF so ascending
// bin == descending value. Exact-value ties are COMMON -> tie-fix required.

// ---------------- K0: init scratch (ws is poisoned 0xAA before every call).
__global__ void k_init(unsigned* counters, unsigned* hist) {
    unsigned t = blockIdx.x * 1024u + threadIdx.x;
    if (t < 64) counters[t] = 0u;
    if (t < NBINS) hist[t] = 0u;
}

// ---------------- K1: stream volume, append candidate indices to global list.
// Tile of 8192 voxels (32KB) DMA'd global->LDS via global_load_lds width=16
// (async, VGPR-free MLP); threshold scan from LDS; block-aggregated append.
__global__ __launch_bounds__(512, 8)
void k_cand(const float4* __restrict__ vol4, unsigned* counters,
            unsigned* __restrict__ cand) {
    __shared__ float4 tile[2048];             // 32KB
    __shared__ unsigned lcnt, gbase;
    __shared__ unsigned cidx[384];
    if (threadIdx.x == 0) lcnt = 0;
    __syncthreads();

    unsigned t = threadIdx.x;
    unsigned lane = t & 63u;
    unsigned w = t >> 6;
    unsigned blockBase4 = blockIdx.x * 2048u; // float4 units

#pragma unroll
    for (unsigned i = 0; i < 4; i++) {
        unsigned f = i * 512u + w * 64u;      // wave-uniform float4 slot base
        const float4* gp = vol4 + blockBase4 + f + lane;
        __builtin_amdgcn_global_load_lds(
            (const __attribute__((address_space(1))) unsigned int*)gp,
            (__attribute__((address_space(3))) unsigned int*)(tile + f),
            16, 0, 0);
    }
    __builtin_amdgcn_s_waitcnt(0);
    __syncthreads();

    unsigned m = 0u;
    float4 v[4];
#pragma unroll
    for (unsigned i = 0; i < 4; i++) v[i] = tile[i * 512u + t];
#pragma unroll
    for (unsigned i = 0; i < 4; i++) {
        m |= (v[i].x > THRESHV ? 1u : 0u) << (4 * i);
        m |= (v[i].y > THRESHV ? 1u : 0u) << (4 * i + 1);
        m |= (v[i].z > THRESHV ? 1u : 0u) << (4 * i + 2);
        m |= (v[i].w > THRESHV ? 1u : 0u) << (4 * i + 3);
    }
    while (m) {
        int b = __ffs(m) - 1;
        m &= m - 1u;
        unsigned f4 = blockBase4 + (unsigned)(b >> 2) * 512u + t;
        cidx[atomicAdd(&lcnt, 1u) & 383u] = f4 * 4u + (unsigned)(b & 3);
    }
    __syncthreads();
    if (threadIdx.x == 0) gbase = atomicAdd(&counters[0], lcnt);
    __syncthreads();
    unsigned n = lcnt > 384u ? 384u : lcnt;
    for (unsigned i = threadIdx.x; i < n; i += 512u) {
        unsigned p = gbase + i;
        if (p < CAND_CAP) cand[p] = cidx[i];
    }
}

// branchless 8-way select: i must be in [0,7] when the result is used.
__device__ __forceinline__ float sel8(const float4& a, const float4& b, int i) {
    float r = a.x;
    r = (i == 1) ? a.y : r;
    r = (i == 2) ? a.z : r;
    r = (i == 3) ? a.w : r;
    r = (i == 4) ? b.x : r;
    r = (i == 5) ? b.y : r;
    r = (i == 6) ? b.z : r;
    r = (i == 7) ? b.w : r;
    return r;
}

// ---------------- K2: THREAD-PER-CANDIDATE verify + centroid. 64 candidates
// per wave; per z-plane 14 independent b128 loads hoisted before consumption;
// branchless x-edge: load 8 floats from e=clamp(x-3,0,504), element d (global
// x-coord g=x-3+d) = in-range ? v[o+d] : 0, o=(x-3)-e in [-3,4]; o+d is in
// [0,7] whenever g is in range (R10 BUG: o in [2,4] was mis-handled -> ~600
// right-edge candidates got garbage -> row-shifts -> absmax 51).
// Thread-local sums; no shuffle reductions. No launch_bounds: VGPRs free.
__global__ void k_verify(const float* __restrict__ vol,
                         const unsigned* __restrict__ cand,
                         unsigned* counters, unsigned* hist,
                         unsigned long long* keys, float4* psums) {
    unsigned nc = counters[0]; if (nc > CAND_CAP) nc = CAND_CAP;
    for (unsigned c = blockIdx.x * 256u + threadIdx.x; c < nc;
         c += gridDim.x * 256u) {
        unsigned idx = cand[c];
        int z = (int)(idx >> 18), y = (int)((idx >> 9) & 511), x = (int)(idx & 511);
        float center = vol[idx];
        int e = x - 3; if (e < 0) e = 0; if (e > 504) e = 504;
        int o = (x - 3) - e;                  // in [-3,4]
        // in-range mask for the 7 row elements (g = x-3+d in [0,511])
        bool inr[7];
#pragma unroll
        for (int d = 0; d < 7; ++d) {
            int g = x - 3 + d;
            inr[d] = (unsigned)g < WW;
        }
        bool kill = false;
        float s0 = 0.f, sx = 0.f, sy = 0.f, sz = 0.f;
#pragma unroll
        for (int dz = 0; dz < 7; ++dz) {
            int nz = z + dz - 3;
            bool zok = (unsigned)nz < DD;
            float4 q0[7], q1[7];
            bool ok[7];
#pragma unroll
            for (int dy = 0; dy < 7; ++dy) {
                int ny = y + dy - 3;
                ok[dy] = zok && ((unsigned)ny < HH);
                unsigned rz = ok[dy] ? (unsigned)nz : (unsigned)z;
                unsigned ry = ok[dy] ? (unsigned)ny : (unsigned)y;
                const float* rp = vol + (((size_t)rz << 18) | ((size_t)ry << 9)) + (unsigned)e;
                q0[dy] = *(const float4*)(rp);
                q1[dy] = *(const float4*)(rp + 4);
            }
#pragma unroll
            for (int dy = 0; dy < 7; ++dy) {
                float rv[7];
#pragma unroll
                for (int d = 0; d < 7; ++d)
                    rv[d] = inr[d] ? sel8(q0[dy], q1[dy], o + d) : 0.f;
                float rowsum = rv[0]+rv[1]+rv[2]+rv[3]+rv[4]+rv[5]+rv[6];
                float rowsx  = -3.f*rv[0] - 2.f*rv[1] - rv[2] + rv[4] + 2.f*rv[5] + 3.f*rv[6];
                float mx = fmaxf(fmaxf(fmaxf(rv[0], rv[1]), fmaxf(rv[2], rv[3])),
                                 fmaxf(fmaxf(rv[4], rv[5]), rv[6]));
                rowsum = ok[dy] ? rowsum : 0.f;
                rowsx  = ok[dy] ? rowsx  : 0.f;
                mx     = ok[dy] ? mx     : 0.f;
                kill = kill || (mx > center);
                s0 += rowsum;
                sx += rowsx;
                sy += rowsum * (float)(dy - 3);
                sz += rowsum * (float)(dz - 3);
            }
        }
        if (!kill) {
            unsigned bits = __float_as_uint(center);
            atomicAdd(&hist[(~bits) & 0xFFFFu], 1u);
            unsigned p = atomicAdd(&counters[1], 1u);
            if (p < PEAK_CAP) {
                keys[p] = ((unsigned long long)bits << 32) | idx;
                psums[p] = make_float4(s0, sx, sy, sz);
            }
        }
    }
}

// ---------------- K3: exclusive prefix sum over 65536 bins (single block),
// uint4-vectorized loads/stores.
__global__ void k_scan(const unsigned* __restrict__ hist, unsigned* cursor) {
    __shared__ unsigned partial[1024];
    int t = threadIdx.x;
    const uint4* h4 = (const uint4*)(hist + t * 64);
    uint4 loc[16];
#pragma unroll
    for (int i = 0; i < 16; i++) loc[i] = h4[i];
    unsigned s = 0;
#pragma unroll
    for (int i = 0; i < 16; i++) s += loc[i].x + loc[i].y + loc[i].z + loc[i].w;
    partial[t] = s;
    __syncthreads();
    for (int off = 1; off < 1024; off <<= 1) {
        unsigned v = (t >= off) ? partial[t - off] : 0u;
        __syncthreads();
        partial[t] += v;
        __syncthreads();
    }
    unsigned run = (t == 0) ? 0u : partial[t - 1];
    uint4* c4 = (uint4*)(cursor + t * 64);
#pragma unroll
    for (int i = 0; i < 16; i++) {
        uint4 h = loc[i]; uint4 o;
        o.x = run; run += h.x;
        o.y = run; run += h.y;
        o.z = run; run += h.z;
        o.w = run; run += h.w;
        c4[i] = o;
    }
}

// ---------------- K4: scatter keys (+slot payload) into descending-value
// order; rows >= np are exactly the all-zero output rows -> zero them here.
__global__ void k_scatter(const unsigned* __restrict__ counters,
                          const unsigned long long* __restrict__ keys,
                          unsigned* cursor, unsigned long long* sorted,
                          unsigned* sslot,
                          float4* __restrict__ out, float* __restrict__ valid) {
    unsigned np = counters[1]; if (np > PEAK_CAP) np = PEAK_CAP;
    unsigned t = blockIdx.x * 1024u + threadIdx.x;
    if (t < np) {
        unsigned long long key = keys[t];
        unsigned bits = (unsigned)(key >> 32);
        unsigned pos = atomicAdd(&cursor[(~bits) & 0xFFFFu], 1u);
        if (pos < PEAK_CAP) { sorted[pos] = key; sslot[pos] = t; }
    } else if (t < KPEAKS) {
        out[t] = make_float4(0.f, 0.f, 0.f, 0.f);
        valid[t] = 0.f;
    }
}

// ---------------- K5: tiefix + output fused. Each scatter position finds its
// tie-corrected row (equal-value runs ordered by ascending voxel idx, per
// lax.top_k) and writes the final output row directly. Bounded by np.
__global__ void k_finish(const unsigned* __restrict__ counters,
                         const unsigned long long* __restrict__ sorted,
                         const unsigned* __restrict__ sslot,
                         const float4* __restrict__ psums,
                         float4* __restrict__ out, float* __restrict__ valid) {
    unsigned np = counters[1]; if (np > PEAK_CAP) np = PEAK_CAP;
    unsigned t = blockIdx.x * 1024u + threadIdx.x;
    if (t >= np) return;
    unsigned long long key = sorted[t];
    unsigned bits = (unsigned)(key >> 32);
    unsigned s = t;
    while (s > 0 && (unsigned)(sorted[s - 1] >> 32) == bits) s--;
    unsigned myidx = (unsigned)key;
    unsigned rank = 0, e = s;
    while (e < np) {
        unsigned long long k2 = sorted[e];
        if ((unsigned)(k2 >> 32) != bits) break;
        if ((unsigned)k2 < myidx) rank++;
        e++;
    }
    unsigned row = s + rank;
    if (row >= KPEAKS) return;
    unsigned idx = myidx;
    int z = idx >> 18, y = (idx >> 9) & 511, x = idx & 511;
    float4 ps = psums[sslot[t]];
    float val = __uint_as_float(bits);
    float xloc = ps.y / ps.x, yloc = ps.z / ps.x, zloc = ps.w / ps.x;
    float xr = ((float)x + xloc - (float)(WW - 1) * 0.5f) * 0.1f;
    float yr = ((float)y + yloc - (float)(HH - 1) * 0.5f) * 0.1f;
    float zr = ((float)z + zloc + 0.5f) * 0.02f - 2.0f;
    out[row] = make_float4(xr, yr, zr, val);
    valid[row] = 1.f;
}

extern "C" void kernel_launch(void* const* d_in, const int* in_sizes, int n_in,
                              void* d_out, int out_size, void* d_ws, size_t ws_size,
                              hipStream_t stream) {
    const float* vol = (const float*)d_in[0];
    // d_in[1] = max_peaks scalar (device); fixed at 131072 for this problem.

    char* w = (char*)d_ws;
    unsigned* counters = (unsigned*)w;                                   // 1 KB
    unsigned* hist     = (unsigned*)(w + 1024);                          // 256 KB
    unsigned* cursor   = (unsigned*)(w + 1024 + NBINS * 4);              // 256 KB
    unsigned* cand     = (unsigned*)(w + 1024 + 2 * NBINS * 4);          // 2 MB
    char* w2 = w + 1024 + 2 * NBINS * 4 + CAND_CAP * 4;
    unsigned long long* keys   = (unsigned long long*)w2;                // 2 MB
    unsigned long long* sorted = keys + PEAK_CAP;                        // 2 MB
    unsigned* sslot = (unsigned*)(sorted + PEAK_CAP);                    // 1 MB
    float4*   psums = (float4*)(sslot + PEAK_CAP);                       // 4 MB
    // total ~11.5 MB of ws

    float* out_rows = (float*)d_out;                 // (131072, 4)
    float* valid = out_rows + (size_t)KPEAKS * 4;    // (131072,)

    k_init<<<NBINS / 1024, 1024, 0, stream>>>(counters, hist);
    k_cand<<<NVOX / 8192, 512, 0, stream>>>((const float4*)vol, counters, cand);
    k_verify<<<1024, 256, 0, stream>>>(vol, cand, counters, hist, keys, psums);
    k_scan<<<1, 1024, 0, stream>>>(hist, cursor);
    k_scatter<<<PEAK_CAP / 1024, 1024, 0, stream>>>(counters, keys, cursor, sorted, sslot,
                                                    (float4*)out_rows, valid);
    k_finish<<<PEAK_CAP / 1024, 1024, 0, stream>>>(counters, sorted, sslot, psums,
                                                   (float4*)out_rows, valid);
}

// Round 12
// 255.773 us; speedup vs baseline: 1.9993x; 1.9993x over previous
//
#include <hip/hip_runtime.h>

#define DD 128
#define HH 512
#define WW 512
#define NVOX (DD*HH*WW)          // 33554432
#define THRESHV 0.997f
#define KPEAKS 131072
#define PEAK_CAP (1u<<18)        // 262144 peak slots (expect ~63K)
#define NBINS 65536

// peaks all lie in (0.997, 1.0): float bits have constant upper 16 bits
// 0x3F7F -> low 16 bits monotone in value. bin=(~bits)&0xFFFF so ascending
// bin == descending value. Exact-value ties are COMMON -> tie-fix required.
//
// R12 = R8 rollback. R9 (aligned 3-load), R10/R11 (thread-per-candidate)
// all regressed; R8/R9 deltas fit a TA line-lookup model (~4cy per distinct
// 64B line per vmem instruction per CU) under which R8's phase B is within
// ~20% of the structural floor for this access pattern.

// ---------------- K0: init scratch (ws is poisoned 0xAA before every call).
__global__ void k_init(unsigned* counters, unsigned* hist) {
    unsigned t = blockIdx.x * 1024u + threadIdx.x;
    if (t < 64) counters[t] = 0u;
    if (t < NBINS) hist[t] = 0u;
}

// ---------------- K1: FUSED stream + verify + centroid. 512 thr x 4096 blk.
// Phase A: tile of 8192 voxels (32KB) DMA'd global->LDS via
// __builtin_amdgcn_global_load_lds width=16 (async, VGPR-free MLP).
// Phase B: wave per candidate PAIR: lane l<49 owns row (dz=l/7, dy=l%7) =
// 2 unaligned dwordx4; all 4 row-loads of the pair issued before use;
// center via __shfl(rv[3], 24); shuffle-reduce 4 sums.
__global__ __launch_bounds__(512, 8)
void k_find(const float4* __restrict__ vol4, const float* __restrict__ vol,
            unsigned* counters, unsigned* hist,
            unsigned long long* keys, float4* psums) {
    __shared__ float4 tile[2048];             // 32KB: the block's voxel tile
    __shared__ unsigned lcnt, pcnt, lbase;
    __shared__ unsigned cidx[384];            // candidate voxel indices (E~25)
    __shared__ unsigned long long lbuf[192];  // surviving peak keys (E~16)
    __shared__ float4 sbuf[192];              // surviving peak centroid sums
    if (threadIdx.x == 0) { lcnt = 0; pcnt = 0; }
    __syncthreads();

    unsigned t = threadIdx.x;
    unsigned lane = t & 63u;
    unsigned w = t >> 6;                      // wave id 0..7 (wave-uniform)
    unsigned blockBase4 = blockIdx.x * 2048u; // float4 units

    // ---- Phase A: async DMA global -> LDS (4 x 16B per thread, all in flight)
#pragma unroll
    for (unsigned i = 0; i < 4; i++) {
        unsigned f = i * 512u + w * 64u;      // wave-uniform float4 slot base
        const float4* gp = vol4 + blockBase4 + f + lane;
        __builtin_amdgcn_global_load_lds(
            (const __attribute__((address_space(1))) unsigned int*)gp,
            (__attribute__((address_space(3))) unsigned int*)(tile + f),
            16, 0, 0);
    }
    __builtin_amdgcn_s_waitcnt(0);
    __syncthreads();

    // ---- threshold scan from LDS
    unsigned m = 0u;
    float4 v[4];
#pragma unroll
    for (unsigned i = 0; i < 4; i++) v[i] = tile[i * 512u + t];
#pragma unroll
    for (unsigned i = 0; i < 4; i++) {
        m |= (v[i].x > THRESHV ? 1u : 0u) << (4 * i);
        m |= (v[i].y > THRESHV ? 1u : 0u) << (4 * i + 1);
        m |= (v[i].z > THRESHV ? 1u : 0u) << (4 * i + 2);
        m |= (v[i].w > THRESHV ? 1u : 0u) << (4 * i + 3);
    }
    while (m) {
        int b = __ffs(m) - 1;
        m &= m - 1u;
        unsigned f4 = blockBase4 + (unsigned)(b >> 2) * 512u + t;
        cidx[atomicAdd(&lcnt, 1u) & 383u] = f4 * 4u + (unsigned)(b & 3);
    }
    __syncthreads();

    // ---- Phase B: verify, 2 candidates per wave iteration (8 waves)
    unsigned n = lcnt > 384u ? 384u : lcnt;
    int dz = (int)lane / 7, dy = (int)lane - dz * 7;   // meaningful for lane<49
    for (unsigned base = w * 2u; base < n; base += 16u) {
        bool has2 = (base + 1u < n);
        unsigned idxA = cidx[base];
        unsigned idxB = has2 ? cidx[base + 1u] : idxA;
        int zA = idxA >> 18, yA = (idxA >> 9) & 511, xA = idxA & 511;
        int zB = idxB >> 18, yB = (idxB >> 9) & 511, xB = idxB & 511;
        int nzA = zA + dz - 3, nyA = yA + dy - 3;
        int nzB = zB + dz - 3, nyB = yB + dy - 3;
        bool rowokA = (lane < 49) && ((unsigned)nzA < DD) && ((unsigned)nyA < HH);
        bool rowokB = (lane < 49) && ((unsigned)nzB < DD) && ((unsigned)nyB < HH);
        size_t rbA = rowokA ? (((size_t)(unsigned)nzA << 18) | ((size_t)(unsigned)nyA << 9))
                            : (((size_t)zA << 18) | ((size_t)yA << 9));
        size_t rbB = rowokB ? (((size_t)(unsigned)nzB << 18) | ((size_t)(unsigned)nyB << 9))
                            : (((size_t)zB << 18) | ((size_t)yB << 9));
        float rvA[7], rvB[7];
        bool intAB = (xA >= 3) && (xA <= WW - 4) && (xB >= 3) && (xB <= WW - 4);
        if (intAB) {
            float4 fA0 = *(const float4*)(vol + rbA + (unsigned)(xA - 3));
            float4 fA1 = *(const float4*)(vol + rbA + (unsigned)(xA + 1));
            float4 fB0 = *(const float4*)(vol + rbB + (unsigned)(xB - 3));
            float4 fB1 = *(const float4*)(vol + rbB + (unsigned)(xB + 1));
            rvA[0] = fA0.x; rvA[1] = fA0.y; rvA[2] = fA0.z; rvA[3] = fA0.w;
            rvA[4] = fA1.x; rvA[5] = fA1.y; rvA[6] = fA1.z;
            rvB[0] = fB0.x; rvB[1] = fB0.y; rvB[2] = fB0.z; rvB[3] = fB0.w;
            rvB[4] = fB1.x; rvB[5] = fB1.y; rvB[6] = fB1.z;
        } else {
            // rare x-edge path (wave-uniform): clamped scalar loads
#pragma unroll
            for (int d = 0; d < 7; d++) {
                int nxA = xA + d - 3;
                bool okA = (unsigned)nxA < WW;
                float va = vol[rbA + (unsigned)(okA ? nxA : xA)];
                rvA[d] = okA ? va : 0.f;
                int nxB = xB + d - 3;
                bool okB = (unsigned)nxB < WW;
                float vb = vol[rbB + (unsigned)(okB ? nxB : xB)];
                rvB[d] = okB ? vb : 0.f;
            }
        }
        if (!rowokA) {
#pragma unroll
            for (int d = 0; d < 7; d++) rvA[d] = 0.f;
        }
        if (!rowokB) {
#pragma unroll
            for (int d = 0; d < 7; d++) rvB[d] = 0.f;
        }
        float centerA = __shfl(rvA[3], 24);
        float centerB = __shfl(rvB[3], 24);

        // ---- candidate A
        {
            bool kill = false;
            float s0r = 0.f, sxr = 0.f;
#pragma unroll
            for (int d = 0; d < 7; d++) {
                kill |= rvA[d] > centerA;
                s0r += rvA[d];
                sxr += rvA[d] * (float)(d - 3);
            }
            if (!__any(kill)) {
                float s0 = s0r, sx = sxr;
                float sy = s0r * (float)(dy - 3);
                float sz = s0r * (float)(dz - 3);
                for (int off = 32; off; off >>= 1) {
                    s0 += __shfl_down(s0, off);
                    sx += __shfl_down(sx, off);
                    sy += __shfl_down(sy, off);
                    sz += __shfl_down(sz, off);
                }
                if (lane == 0) {
                    unsigned bits = __float_as_uint(centerA);
                    atomicAdd(&hist[(~bits) & 0xFFFFu], 1u);
                    unsigned li = atomicAdd(&pcnt, 1u);
                    if (li < 192u) {
                        lbuf[li] = ((unsigned long long)bits << 32) | idxA;
                        sbuf[li] = make_float4(s0, sx, sy, sz);
                    }
                }
            }
        }
        // ---- candidate B
        if (has2) {
            bool kill = false;
            float s0r = 0.f, sxr = 0.f;
#pragma unroll
            for (int d = 0; d < 7; d++) {
                kill |= rvB[d] > centerB;
                s0r += rvB[d];
                sxr += rvB[d] * (float)(d - 3);
            }
            if (!__any(kill)) {
                float s0 = s0r, sx = sxr;
                float sy = s0r * (float)(dy - 3);
                float sz = s0r * (float)(dz - 3);
                for (int off = 32; off; off >>= 1) {
                    s0 += __shfl_down(s0, off);
                    sx += __shfl_down(sx, off);
                    sy += __shfl_down(sy, off);
                    sz += __shfl_down(sz, off);
                }
                if (lane == 0) {
                    unsigned bits = __float_as_uint(centerB);
                    atomicAdd(&hist[(~bits) & 0xFFFFu], 1u);
                    unsigned li = atomicAdd(&pcnt, 1u);
                    if (li < 192u) {
                        lbuf[li] = ((unsigned long long)bits << 32) | idxB;
                        sbuf[li] = make_float4(s0, sx, sy, sz);
                    }
                }
            }
        }
    }
    __syncthreads();
    if (threadIdx.x == 0) lbase = atomicAdd(&counters[1], pcnt);
    __syncthreads();
    unsigned np = pcnt > 192u ? 192u : pcnt;
    for (unsigned i = threadIdx.x; i < np; i += 512u) {
        unsigned p = lbase + i;
        if (p < PEAK_CAP) { keys[p] = lbuf[i]; psums[p] = sbuf[i]; }
    }
}

// ---------------- K2: exclusive prefix sum over 65536 bins (single block),
// uint4-vectorized loads/stores.
__global__ void k_scan(const unsigned* __restrict__ hist, unsigned* cursor) {
    __shared__ unsigned partial[1024];
    int t = threadIdx.x;
    const uint4* h4 = (const uint4*)(hist + t * 64);
    uint4 loc[16];
#pragma unroll
    for (int i = 0; i < 16; i++) loc[i] = h4[i];
    unsigned s = 0;
#pragma unroll
    for (int i = 0; i < 16; i++) s += loc[i].x + loc[i].y + loc[i].z + loc[i].w;
    partial[t] = s;
    __syncthreads();
    for (int off = 1; off < 1024; off <<= 1) {
        unsigned v = (t >= off) ? partial[t - off] : 0u;
        __syncthreads();
        partial[t] += v;
        __syncthreads();
    }
    unsigned run = (t == 0) ? 0u : partial[t - 1];
    uint4* c4 = (uint4*)(cursor + t * 64);
#pragma unroll
    for (int i = 0; i < 16; i++) {
        uint4 h = loc[i]; uint4 o;
        o.x = run; run += h.x;
        o.y = run; run += h.y;
        o.z = run; run += h.z;
        o.w = run; run += h.w;
        c4[i] = o;
    }
}

// ---------------- K3: scatter keys (+slot payload) into descending-value
// order; rows >= np are exactly the all-zero output rows -> zero them here.
__global__ void k_scatter(const unsigned* __restrict__ counters,
                          const unsigned long long* __restrict__ keys,
                          unsigned* cursor, unsigned long long* sorted,
                          unsigned* sslot,
                          float4* __restrict__ out, float* __restrict__ valid) {
    unsigned np = counters[1]; if (np > PEAK_CAP) np = PEAK_CAP;
    unsigned t = blockIdx.x * 1024u + threadIdx.x;
    if (t < np) {
        unsigned long long key = keys[t];
        unsigned bits = (unsigned)(key >> 32);
        unsigned pos = atomicAdd(&cursor[(~bits) & 0xFFFFu], 1u);
        if (pos < PEAK_CAP) { sorted[pos] = key; sslot[pos] = t; }
    } else if (t < KPEAKS) {
        out[t] = make_float4(0.f, 0.f, 0.f, 0.f);
        valid[t] = 0.f;
    }
}

// ---------------- K4: tiefix + output fused. Each scatter position finds its
// tie-corrected row (equal-value runs ordered by ascending voxel idx, per
// lax.top_k) and writes the final output row directly. Bounded by np.
__global__ void k_finish(const unsigned* __restrict__ counters,
                         const unsigned long long* __restrict__ sorted,
                         const unsigned* __restrict__ sslot,
                         const float4* __restrict__ psums,
                         float4* __restrict__ out, float* __restrict__ valid) {
    unsigned np = counters[1]; if (np > PEAK_CAP) np = PEAK_CAP;
    unsigned t = blockIdx.x * 1024u + threadIdx.x;
    if (t >= np) return;
    unsigned long long key = sorted[t];
    unsigned bits = (unsigned)(key >> 32);
    unsigned s = t;
    while (s > 0 && (unsigned)(sorted[s - 1] >> 32) == bits) s--;
    unsigned myidx = (unsigned)key;
    unsigned rank = 0, e = s;
    while (e < np) {
        unsigned long long k2 = sorted[e];
        if ((unsigned)(k2 >> 32) != bits) break;
        if ((unsigned)k2 < myidx) rank++;
        e++;
    }
    unsigned row = s + rank;
    if (row >= KPEAKS) return;
    unsigned idx = myidx;
    int z = idx >> 18, y = (idx >> 9) & 511, x = idx & 511;
    float4 ps = psums[sslot[t]];
    float val = __uint_as_float(bits);
    float xloc = ps.y / ps.x, yloc = ps.z / ps.x, zloc = ps.w / ps.x;
    float xr = ((float)x + xloc - (float)(WW - 1) * 0.5f) * 0.1f;
    float yr = ((float)y + yloc - (float)(HH - 1) * 0.5f) * 0.1f;
    float zr = ((float)z + zloc + 0.5f) * 0.02f - 2.0f;
    out[row] = make_float4(xr, yr, zr, val);
    valid[row] = 1.f;
}

extern "C" void kernel_launch(void* const* d_in, const int* in_sizes, int n_in,
                              void* d_out, int out_size, void* d_ws, size_t ws_size,
                              hipStream_t stream) {
    const float* vol = (const float*)d_in[0];
    // d_in[1] = max_peaks scalar (device); fixed at 131072 for this problem.

    char* w = (char*)d_ws;
    unsigned* counters = (unsigned*)w;                                   // 1 KB
    unsigned* hist     = (unsigned*)(w + 1024);                          // 256 KB
    unsigned* cursor   = (unsigned*)(w + 1024 + NBINS * 4);              // 256 KB
    char* w2 = w + 1024 + 2 * NBINS * 4;
    unsigned long long* keys   = (unsigned long long*)w2;                // 2 MB
    unsigned long long* sorted = keys + PEAK_CAP;                        // 2 MB
    unsigned* sslot = (unsigned*)(sorted + PEAK_CAP);                    // 1 MB
    float4*   psums = (float4*)(sslot + PEAK_CAP);                       // 4 MB
    // total ~9.5 MB of ws

    float* out_rows = (float*)d_out;                 // (131072, 4)
    float* valid = out_rows + (size_t)KPEAKS * 4;    // (131072,)

    k_init<<<NBINS / 1024, 1024, 0, stream>>>(counters, hist);
    k_find<<<NVOX / 8192, 512, 0, stream>>>((const float4*)vol, vol, counters, hist, keys, psums);
    k_scan<<<1, 1024, 0, stream>>>(hist, cursor);
    k_scatter<<<PEAK_CAP / 1024, 1024, 0, stream>>>(counters, keys, cursor, sorted, sslot,
                                                    (float4*)out_rows, valid);
    k_finish<<<PEAK_CAP / 1024, 1024, 0, stream>>>(counters, sorted, sslot, psums,
                                                   (float4*)out_rows, valid);
}